// Round 1
// baseline (708.906 us; speedup 1.0000x reference)
//
#include <hip/hip_runtime.h>
#include <math.h>

// Problem constants
#define BB    32
#define CIN   64
#define HH    32
#define WW    32
#define COUT  128
#define PP    1024      // HH*WW
#define OTILE 8         // output channels per block
#define PTILE 256       // pixels per block (4 waves x 64 px = 8 rows)

// inv_denom = 1/(2*1.5*0.025) = 13.3333, shift = 0.1*inv_denom = 1.3333
// Work in log2 domain: Z = z*log2(e).
static constexpr float SCALE    = 19.235933878519513f;   // inv_denom * log2(e)
static constexpr float SBITS    = 1.9235933878519513f;   // shift * log2(e)
static constexpr float M2P      = 3.7936678946831774f;   // 2^SBITS  = e^shift
static constexpr float M2N      = 0.26359713811572677f;  // 2^-SBITS = e^-shift
static constexpr float OUTSCALE = 2.7025482032898827e-05f; // ALPHA*R*ln2^2
static constexpr float ZCUT     = 8.0f;   // skip if all-lane Z < -8 (z < -0.416*...; residual ~e^-12, negligible)
static constexpr float INVSCALE = 0.051986038544710014f; // 1/SCALE

__global__ __launch_bounds__(256) void nlconv_kernel(
    const float* __restrict__ x,      // [B, CIN, 32, 32]
    const float* __restrict__ theta,  // [COUT, CIN, 3, 3]
    float* __restrict__ out)          // [B, COUT, 32, 32]
{
    const int t  = threadIdx.x;
    const int b  = blockIdx.x;          // image
    const int pt = blockIdx.y;          // pixel tile (0..3)
    const int ot = blockIdx.z;          // out-channel tile (0..15)
    const int p  = pt * PTILE + t;      // pixel index in [0,1024)
    const int py = p >> 5;
    const int px = p & 31;
    const int o0 = ot * OTILE;

    // 3x3 neighborhood: clamped offset + zero-pad mask folded into the scale
    int   off[9];
    float msc[9];
#pragma unroll
    for (int dy = 0; dy < 3; ++dy) {
#pragma unroll
        for (int dx = 0; dx < 3; ++dx) {
            int yy = py + dy - 1;
            int xx = px + dx - 1;
            bool ok = (yy >= 0) && (yy < HH) && (xx >= 0) && (xx < WW);
            int yc = min(max(yy, 0), HH - 1);
            int xc = min(max(xx, 0), WW - 1);
            off[dy * 3 + dx] = yc * WW + xc;
            msc[dy * 3 + dx] = ok ? SCALE : 0.0f;   // pad -> xi = 0 (true padded value)
        }
    }

    const float* xb = x + (size_t)b * (CIN * PP);

    float acc[OTILE];
#pragma unroll
    for (int i = 0; i < OTILE; ++i) acc[i] = 0.0f;

    for (int c = 0; c < CIN; ++c) {
        const float* xc = xb + c * PP;

        // Load 3x3 patch, pre-scaled into log2 domain. Track lane max.
        float xi[9];
        float m = 0.0f;  // padded zeros contribute xi=0 anyway; interior lanes overwritten below
        m = -3.0e38f;
#pragma unroll
        for (int k = 0; k < 9; ++k) {
            xi[k] = xc[off[k]] * msc[k];
            m = fmaxf(m, xi[k]);
        }
        // wave-wide max over 64 lanes
#pragma unroll
        for (int s = 32; s > 0; s >>= 1)
            m = fmaxf(m, __shfl_xor(m, s));

        // body runs iff theta < tcut  (else all lanes have Z < -ZCUT -> term ~ e^{2z} negligible)
        const float tcut = (m + ZCUT) * INVSCALE;

        const float* tc = theta + (size_t)(o0 * CIN + c) * 9;
#pragma unroll
        for (int o = 0; o < OTILE; ++o) {
            const float* tr = tc + (size_t)o * (CIN * 9);
#pragma unroll
            for (int k = 0; k < 9; ++k) {
                float th = tr[k];
                if (th < tcut) {
                    // Z = (x - theta)*inv_denom*log2e
                    float Z    = fmaf(th, -SCALE, xi[k]);
                    float cc   = exp2f(-fabsf(Z));          // 2^{-|Z|}, never overflows
                    bool  pos  = Z >= 0.0f;
                    float L1   = __log2f(1.0f + cc);
                    float L2   = __log2f(fmaf(cc, pos ? M2P : M2N, 1.0f));
                    float base = fmaxf(Z, 0.0f);
                    float sp1  = base + L1;                        // softplus(z)/ln2
                    float sp2  = base - (pos ? SBITS : 0.0f) + L2; // softplus(z-s)/ln2
                    acc[o] = fmaf(sp1 - sp2, sp1 + sp2, acc[o]);   // sp1^2 - sp2^2
                }
            }
        }
    }

    float* ob = out + ((size_t)b * COUT + o0) * PP + p;
#pragma unroll
    for (int o = 0; o < OTILE; ++o) {
        float v = acc[o] * OUTSCALE;
        v = fminf(fmaxf(v, 0.0f), 9.0f);
        ob[(size_t)o * PP] = v;
    }
}

extern "C" void kernel_launch(void* const* d_in, const int* in_sizes, int n_in,
                              void* d_out, int out_size, void* d_ws, size_t ws_size,
                              hipStream_t stream) {
    const float* x     = (const float*)d_in[0];  // [32,64,32,32]
    const float* theta = (const float*)d_in[1];  // [128,64,3,3]
    float* out         = (float*)d_out;          // [32,128,32,32]

    dim3 grid(BB, PP / PTILE, COUT / OTILE);     // 32 x 4 x 16 = 2048 blocks
    dim3 block(256);
    nlconv_kernel<<<grid, block, 0, stream>>>(x, theta, out);
}

// Round 2
// 574.222 us; speedup vs baseline: 1.2345x; 1.2345x over previous
//
#include <hip/hip_runtime.h>
#include <math.h>

// Problem constants
#define BB    32
#define CIN   64
#define HH    32
#define WW    32
#define COUT  128
#define PP    1024      // HH*WW
#define OTILE 8         // output channels per block
#define PTILE 256       // pixels per block (4 waves x 64 px = 2 rows each)

// inv_denom = 1/(2*1.5*0.025) = 13.3333, shift = 0.1*inv_denom = 1.3333
// Work in log2 domain: Z = z*log2(e).
static constexpr float SCALE    = 19.235933878519513f;   // inv_denom * log2(e)
static constexpr float SBITS    = 1.9235933878519513f;   // shift * log2(e)
static constexpr float M2N      = 0.26359713811572677f;  // 2^-SBITS = e^-shift
static constexpr float OUTSCALE = 2.7025482032898827e-05f; // ALPHA*R*ln2^2
static constexpr float ZCUT     = 5.0f;   // skip term if all lanes Z < -5: residual ~4^-5*0.93*576*OUTSCALE ~ 1.4e-5
static constexpr float INVSCALE = 0.051986038544710014f; // 1/SCALE

__global__ __launch_bounds__(256, 4) void nlconv_kernel(
    const float* __restrict__ x,      // [B, CIN, 32, 32]
    const float* __restrict__ theta,  // [COUT, CIN, 3, 3]
    float* __restrict__ out)          // [B, COUT, 32, 32]
{
    const int t  = threadIdx.x;
    const int b  = blockIdx.x;          // image
    const int pt = blockIdx.y;          // pixel tile (0..3)
    const int ot = blockIdx.z;          // out-channel tile (0..15)
    const int p  = pt * PTILE + t;      // pixel index in [0,1024)
    const int py = p >> 5;
    const int px = p & 31;
    const int o0 = ot * OTILE;

    // 3x3 neighborhood: clamped offset + zero-pad mask folded into the scale
    int   off[9];
    float msc[9];
#pragma unroll
    for (int dy = 0; dy < 3; ++dy) {
#pragma unroll
        for (int dx = 0; dx < 3; ++dx) {
            int yy = py + dy - 1;
            int xx = px + dx - 1;
            bool ok = (yy >= 0) && (yy < HH) && (xx >= 0) && (xx < WW);
            int yc = min(max(yy, 0), HH - 1);
            int xc = min(max(xx, 0), WW - 1);
            off[dy * 3 + dx] = yc * WW + xc;
            msc[dy * 3 + dx] = ok ? SCALE : 0.0f;   // pad -> xi = 0 (true padded value)
        }
    }

    const float* xb = x + (size_t)b * (CIN * PP);

    float acc[OTILE];
#pragma unroll
    for (int i = 0; i < OTILE; ++i) acc[i] = 0.0f;

    // prime the x pipeline (c = 0)
    float xi[9];
#pragma unroll
    for (int k = 0; k < 9; ++k) xi[k] = xb[off[k]] * msc[k];

    for (int c = 0; c < CIN; ++c) {
        // prefetch next channel's patch (clamped pointer keeps it in-bounds; result
        // unused on the last iteration)
        const float* xcn = xb + (size_t)min(c + 1, CIN - 1) * PP;
        float xn[9];
#pragma unroll
        for (int k = 0; k < 9; ++k) xn[k] = xcn[off[k]] * msc[k];

        // wave-max of xi over all 9 offsets and 64 lanes
        float m = xi[0];
#pragma unroll
        for (int k = 1; k < 9; ++k) m = fmaxf(m, xi[k]);
#pragma unroll
        for (int s = 32; s > 0; s >>= 1)
            m = fmaxf(m, __shfl_xor(m, s));

        // scalarize the cut -> uniform branch (s_cbranch), not exec predication
        const float cut = __uint_as_float(
            __builtin_amdgcn_readfirstlane(__float_as_uint((m + ZCUT) * INVSCALE)));

        const float* tc = theta + (size_t)(o0 * CIN + c) * 9;
#pragma unroll
        for (int o = 0; o < OTILE; ++o) {
            const float* tr = tc + (size_t)o * (CIN * 9);
#pragma unroll
            for (int k = 0; k < 9; ++k) {
                const float th = tr[k];   // uniform -> SGPR
                if (th < cut) {           // uniform scalar test -> real branch
                    float Zr  = fmaf(th, -SCALE, xi[k]);     // Z = (x - theta)*SCALE (log2 units)
                    float Zc  = fminf(Zr, 60.0f);            // overflow clamp for the exp path
                    float E   = __builtin_amdgcn_exp2f(Zc);  // 2^Z
                    float n1  = 1.0f + E;
                    float n2  = fmaf(E, M2N, 1.0f);          // 1 + 2^(Z-S)
                    float sp1 = __builtin_amdgcn_logf(n1);   // log2 -> softplus(z)/ln2
                    float sp2 = __builtin_amdgcn_logf(n2);   // log2 -> softplus(z-s)/ln2
                    float tv  = (sp1 - sp2) * (sp1 + sp2);   // sp1^2 - sp2^2
                    float tL  = fmaf(2.0f * SBITS, Zr, -SBITS * SBITS); // exact linear tail
                    tv = (Zr > 24.0f) ? tL : tv;
                    acc[o] += tv;
                }
            }
        }

#pragma unroll
        for (int k = 0; k < 9; ++k) xi[k] = xn[k];
    }

    float* ob = out + ((size_t)b * COUT + o0) * PP + p;
#pragma unroll
    for (int o = 0; o < OTILE; ++o) {
        float v = acc[o] * OUTSCALE;
        v = fminf(fmaxf(v, 0.0f), 9.0f);
        ob[(size_t)o * PP] = v;
    }
}

extern "C" void kernel_launch(void* const* d_in, const int* in_sizes, int n_in,
                              void* d_out, int out_size, void* d_ws, size_t ws_size,
                              hipStream_t stream) {
    const float* x     = (const float*)d_in[0];  // [32,64,32,32]
    const float* theta = (const float*)d_in[1];  // [128,64,3,3]
    float* out         = (float*)d_out;          // [32,128,32,32]

    dim3 grid(BB, PP / PTILE, COUT / OTILE);     // 32 x 4 x 16 = 2048 blocks
    dim3 block(256);
    nlconv_kernel<<<grid, block, 0, stream>>>(x, theta, out);
}